// Round 12
// baseline (117.526 us; speedup 1.0000x reference)
//
#include <hip/hip_runtime.h>

// Receptive-field spike encoder:
//   out[t, b, d] = ( clip( (int)(scaling[d] * |x[b] - center[d]|), 0, T-1 ) == t ) ? 1 : 0
// Output [T, B, N=16] float32, 512 MiB -> write-BW-bound.
//
// Round-12: lockstep plane march (exact fillBuffer shape). 2048 blocks x 256
// threads = 524288 threads; thread g owns quarter-row g (b = g>>2, fields
// qt = g&3) of EVERY t-plane and loops t = 0..T-1 striding one plane (8 MiB)
// per iteration. The entire chip writes one contiguous 8 MiB window that
// marches forward — fillBuffer's structure (it strides by gridSize*16B too).
// Spike times are computed ONCE per thread; the steady-state loop is
// 4 cmp + 4 cndmask + 1 plain dwordx4 store + 1 addr add, zero loads.
// Per-instruction coalescing unchanged: lane i stores 16 B at base + i*16
// (contiguous aligned 1 KiB per wave-instruction). Plain stores (round-11
// winner). Bounds-guarded; no pragma-unroll tricks (round-7 flake hygiene).

typedef float f32x4 __attribute__((ext_vector_type(4)));

__global__ void __launch_bounds__(256)
rf_encode_march(const float* __restrict__ x,
                const float* __restrict__ center,
                const float* __restrict__ scaling,
                float* __restrict__ out,
                int B, int T) {
    const int g = blockIdx.x * blockDim.x + threadIdx.x;   // [0, 4B)
    if (g >= B * 4) return;
    const int b  = g >> 2;
    const int qt = g & 3;   // which 4 of the 16 receptive fields

    const f32x4 c4 = reinterpret_cast<const f32x4*>(center)[qt];
    const f32x4 s4 = reinterpret_cast<const f32x4*>(scaling)[qt];
    const float xb = x[b];

    // spike times (t-independent): exact numpy op sequence sub,abs,mul,int,clip
    int s0 = (int)(s4.x * fabsf(xb - c4.x)); s0 = min(max(s0, 0), T - 1);
    int s1 = (int)(s4.y * fabsf(xb - c4.y)); s1 = min(max(s1, 0), T - 1);
    int s2 = (int)(s4.z * fabsf(xb - c4.z)); s2 = min(max(s2, 0), T - 1);
    int s3 = (int)(s4.w * fabsf(xb - c4.w)); s3 = min(max(s3, 0), T - 1);

    f32x4* o = reinterpret_cast<f32x4*>(out) + g;    // chunk g of plane 0
    const long long pstride = (long long)B * 4;      // 16B-chunks per plane

    #pragma unroll 4
    for (int t = 0; t < T; ++t) {
        f32x4 r;
        r.x = (s0 == t) ? 1.0f : 0.0f;
        r.y = (s1 == t) ? 1.0f : 0.0f;
        r.z = (s2 == t) ? 1.0f : 0.0f;
        r.w = (s3 == t) ? 1.0f : 0.0f;
        *o = r;
        o += pstride;
    }
}

// generic fallback (N != 16 or B not a multiple of 64)
__global__ void rf_encode_generic(const float* __restrict__ x,
                                  const float* __restrict__ center,
                                  const float* __restrict__ scaling,
                                  float* __restrict__ out,
                                  int B, int N, int T) {
    long long tid = (long long)blockIdx.x * blockDim.x + threadIdx.x;
    long long total = (long long)T * B;
    if (tid >= total) return;
    int b = (int)(tid % B);
    int t = (int)(tid / B);
    float xb = x[b];
    float* o = out + ((long long)t * B + (long long)b) * N;
    for (int d = 0; d < N; ++d) {
        float dist = fabsf(xb - center[d]);
        int v = (int)(scaling[d] * dist);
        v = min(max(v, 0), T - 1);
        o[d] = (v == t) ? 1.0f : 0.0f;
    }
}

extern "C" void kernel_launch(void* const* d_in, const int* in_sizes, int n_in,
                              void* d_out, int out_size, void* d_ws, size_t ws_size,
                              hipStream_t stream) {
    const float* x       = (const float*)d_in[0];
    const float* center  = (const float*)d_in[1];
    const float* scaling = (const float*)d_in[2];
    float* out = (float*)d_out;

    int B = in_sizes[0];
    int N = in_sizes[1];
    int T = (int)((long long)out_size / ((long long)B * (long long)N));

    if (N == 16 && (B % 64) == 0) {
        const int block = 256;
        int nblocks = (B * 4 + block - 1) / block;   // 4B threads, 1 plane/pass
        rf_encode_march<<<nblocks, block, 0, stream>>>(x, center, scaling, out, B, T);
    } else {
        long long total = (long long)T * B;
        const int block = 256;
        int blocks = (int)((total + block - 1) / block);
        rf_encode_generic<<<blocks, block, 0, stream>>>(x, center, scaling, out, B, N, T);
    }
}

// Round 13
// 101.926 us; speedup vs baseline: 1.1531x; 1.1531x over previous
//
#include <hip/hip_runtime.h>

// Receptive-field spike encoder:
//   out[t, b, d] = ( clip( (int)(scaling[d] * |x[b] - center[d]|), 0, T-1 ) == t ) ? 1 : 0
// Output [T, B, N=16] float32, 512 MiB -> write-BW-bound.
//
// Round-13: round-11 winner (2048 blocks x contiguous 256 KiB chunks, plain
// stores, 98.3 us) + ONE change: XCD-aware block->chunk swizzle (T1).
// Default dispatch round-robins consecutive blockIdx.x across the 8 XCDs, so
// each XCD's private-L2 write stream hops in 2 MiB strides. Swizzle
// cb = (bid%8)*(grid/8) + bid/8 gives each XCD one contiguous 64 MiB span ->
// every per-L2 write stream marches linearly. Bijective since grid%8==0.
// Everything else byte-identical to round 11.

typedef float f32x4 __attribute__((ext_vector_type(4)));

#define SUBS  4   // 64 KiB sub-chunks per block -> 256 KiB per block
#define ITERS 16  // 16B chunks per thread per sub-chunk

__global__ void __launch_bounds__(256)
rf_encode_lin(const float* __restrict__ x,
              const float* __restrict__ center,
              const float* __restrict__ scaling,
              float* __restrict__ out,
              int logB, int Bmask, int T) {
    const int lane = threadIdx.x & 63;
    const int wave = threadIdx.x >> 6;
    const int qt   = lane & 3;   // which 4 of the 16 receptive fields

    // XCD-aware swizzle: XCD k owns a contiguous 1/8 of the output
    const int bid  = blockIdx.x;
    const int ncpx = gridDim.x >> 3;                    // chunks per XCD
    const int cb   = (bid & 7) * ncpx + (bid >> 3);     // bijective (grid%8==0)

    const f32x4 c4 = reinterpret_cast<const f32x4*>(center)[qt];
    const f32x4 s4 = reinterpret_cast<const f32x4*>(scaling)[qt];

    // block owns 256 KiB = 4096 rows, all within ONE t-plane (B % 4096 == 0)
    const long long blockRow0 = (long long)cb << 12;   // * 4096 rows
    const int t       = (int)(blockRow0 >> logB);      // block-uniform
    const int rowBase = (int)(blockRow0 & Bmask);      // first b of block

    for (int s = 0; s < SUBS; ++s) {
        // this sub-chunk: 64 KiB = 1024 rows
        const int subRow0 = rowBase + s * 1024 + wave * 256 + (lane >> 2);

        // preload the 16 x-values for this sub-chunk
        float xv[ITERS];
        #pragma unroll
        for (int it = 0; it < ITERS; ++it)
            xv[it] = x[subRow0 + it * 16];

        // wave owns a contiguous 16 KiB run within the sub-chunk
        f32x4* o = reinterpret_cast<f32x4*>(out)
                 + (((long long)cb << 14) + (s << 12) + (wave << 10) + lane);

        #pragma unroll
        for (int it = 0; it < ITERS; ++it) {
            const float xb = xv[it];
            // exact numpy op sequence: sub, abs, mul, trunc-to-int32, clip
            int v0 = (int)(s4.x * fabsf(xb - c4.x)); v0 = min(max(v0, 0), T - 1);
            int v1 = (int)(s4.y * fabsf(xb - c4.y)); v1 = min(max(v1, 0), T - 1);
            int v2 = (int)(s4.z * fabsf(xb - c4.z)); v2 = min(max(v2, 0), T - 1);
            int v3 = (int)(s4.w * fabsf(xb - c4.w)); v3 = min(max(v3, 0), T - 1);
            f32x4 r;
            r.x = (v0 == t) ? 1.0f : 0.0f;
            r.y = (v1 == t) ? 1.0f : 0.0f;
            r.z = (v2 == t) ? 1.0f : 0.0f;
            r.w = (v3 == t) ? 1.0f : 0.0f;
            o[it * 64] = r;   // plain cached store (round-11 winner)
        }
    }
}

// generic fallback (N != 16, B not pow2, or rows not divisible by 4096)
__global__ void rf_encode_generic(const float* __restrict__ x,
                                  const float* __restrict__ center,
                                  const float* __restrict__ scaling,
                                  float* __restrict__ out,
                                  int B, int N, int T) {
    long long tid = (long long)blockIdx.x * blockDim.x + threadIdx.x;
    long long total = (long long)T * B;
    if (tid >= total) return;
    int b = (int)(tid % B);
    int t = (int)(tid / B);
    float xb = x[b];
    float* o = out + ((long long)t * B + (long long)b) * N;
    for (int d = 0; d < N; ++d) {
        float dist = fabsf(xb - center[d]);
        int v = (int)(scaling[d] * dist);
        v = min(max(v, 0), T - 1);
        o[d] = (v == t) ? 1.0f : 0.0f;
    }
}

extern "C" void kernel_launch(void* const* d_in, const int* in_sizes, int n_in,
                              void* d_out, int out_size, void* d_ws, size_t ws_size,
                              hipStream_t stream) {
    const float* x       = (const float*)d_in[0];
    const float* center  = (const float*)d_in[1];
    const float* scaling = (const float*)d_in[2];
    float* out = (float*)d_out;

    int B = in_sizes[0];
    int N = in_sizes[1];
    int T = (int)((long long)out_size / ((long long)B * (long long)N));

    bool bpow2 = (B & (B - 1)) == 0;
    long long rows = (long long)T * B;
    if (N == 16 && bpow2 && (B % 4096) == 0 && (rows % 4096) == 0
        && (((rows >> 12) & 7) == 0)) {
        int logB = 0;
        while ((1 << logB) < B) ++logB;
        int nblocks = (int)(rows >> 12);   // 4096 rows (256 KiB) per block
        rf_encode_lin<<<nblocks, 256, 0, stream>>>(x, center, scaling, out,
                                                   logB, B - 1, T);
    } else {
        const int block = 256;
        int blocks = (int)((rows + block - 1) / block);
        rf_encode_generic<<<blocks, block, 0, stream>>>(x, center, scaling, out, B, N, T);
    }
}

// Round 14
// 98.818 us; speedup vs baseline: 1.1893x; 1.0315x over previous
//
#include <hip/hip_runtime.h>

// Receptive-field spike encoder — FINAL (round-11 winner, reverted after
// r12/r13 regressions):
//   out[t, b, d] = ( clip( (int)(scaling[d] * |x[b] - center[d]|), 0, T-1 ) == t ) ? 1 : 0
// Output [T, B, N=16] float32, 512 MiB -> write-BW-bound. 98.3 us = 5.46 TB/s
// (~80% of this chip's fillBuffer blit ceiling, 68% of HBM spec peak).
//
// Structure (each element measured, see session ledger):
//  - 2048 blocks x 256 thr, each block owns ONE contiguous 256 KiB chunk of
//    the flat output; all blocks resident (8/CU), chunks march linearly. (+7%)
//  - lane i stores 16 B at base + i*16: each wave store instruction covers a
//    contiguous aligned 1 KiB. (+24% — the big coalescing lever)
//  - wave owns contiguous 16 KiB runs; linear chunk ordering chip-wide. (+17%)
//  - plain cached stores (nt slightly worse at this layout). (+2%)
//  - t block-uniform (chunk never straddles a t-plane), x preloaded.
// Rejected by measurement: low occupancy (-4%), lockstep plane march (-16%),
// XCD swizzle (-4%), nt stores (-2%), extra VALU thinning (null).

typedef float f32x4 __attribute__((ext_vector_type(4)));

#define SUBS  4   // 64 KiB sub-chunks per block -> 256 KiB per block
#define ITERS 16  // 16B chunks per thread per sub-chunk

__global__ void __launch_bounds__(256)
rf_encode_lin(const float* __restrict__ x,
              const float* __restrict__ center,
              const float* __restrict__ scaling,
              float* __restrict__ out,
              int logB, int Bmask, int T) {
    const int lane = threadIdx.x & 63;
    const int wave = threadIdx.x >> 6;
    const int qt   = lane & 3;   // which 4 of the 16 receptive fields

    const f32x4 c4 = reinterpret_cast<const f32x4*>(center)[qt];
    const f32x4 s4 = reinterpret_cast<const f32x4*>(scaling)[qt];

    // block owns 256 KiB = 4096 rows, all within ONE t-plane (B % 4096 == 0)
    const long long blockRow0 = (long long)blockIdx.x << 12;   // * 4096 rows
    const int t       = (int)(blockRow0 >> logB);              // block-uniform
    const int rowBase = (int)(blockRow0 & Bmask);              // first b of block

    for (int s = 0; s < SUBS; ++s) {
        // this sub-chunk: 64 KiB = 1024 rows
        const int subRow0 = rowBase + s * 1024 + wave * 256 + (lane >> 2);

        // preload the 16 x-values for this sub-chunk
        float xv[ITERS];
        #pragma unroll
        for (int it = 0; it < ITERS; ++it)
            xv[it] = x[subRow0 + it * 16];

        // wave owns a contiguous 16 KiB run within the sub-chunk
        f32x4* o = reinterpret_cast<f32x4*>(out)
                 + (((long long)blockIdx.x << 14) + (s << 12) + (wave << 10) + lane);

        #pragma unroll
        for (int it = 0; it < ITERS; ++it) {
            const float xb = xv[it];
            // exact numpy op sequence: sub, abs, mul, trunc-to-int32, clip
            int v0 = (int)(s4.x * fabsf(xb - c4.x)); v0 = min(max(v0, 0), T - 1);
            int v1 = (int)(s4.y * fabsf(xb - c4.y)); v1 = min(max(v1, 0), T - 1);
            int v2 = (int)(s4.z * fabsf(xb - c4.z)); v2 = min(max(v2, 0), T - 1);
            int v3 = (int)(s4.w * fabsf(xb - c4.w)); v3 = min(max(v3, 0), T - 1);
            f32x4 r;
            r.x = (v0 == t) ? 1.0f : 0.0f;
            r.y = (v1 == t) ? 1.0f : 0.0f;
            r.z = (v2 == t) ? 1.0f : 0.0f;
            r.w = (v3 == t) ? 1.0f : 0.0f;
            o[it * 64] = r;   // plain cached store
        }
    }
}

// generic fallback (N != 16, B not pow2, or rows not divisible by 4096)
__global__ void rf_encode_generic(const float* __restrict__ x,
                                  const float* __restrict__ center,
                                  const float* __restrict__ scaling,
                                  float* __restrict__ out,
                                  int B, int N, int T) {
    long long tid = (long long)blockIdx.x * blockDim.x + threadIdx.x;
    long long total = (long long)T * B;
    if (tid >= total) return;
    int b = (int)(tid % B);
    int t = (int)(tid / B);
    float xb = x[b];
    float* o = out + ((long long)t * B + (long long)b) * N;
    for (int d = 0; d < N; ++d) {
        float dist = fabsf(xb - center[d]);
        int v = (int)(scaling[d] * dist);
        v = min(max(v, 0), T - 1);
        o[d] = (v == t) ? 1.0f : 0.0f;
    }
}

extern "C" void kernel_launch(void* const* d_in, const int* in_sizes, int n_in,
                              void* d_out, int out_size, void* d_ws, size_t ws_size,
                              hipStream_t stream) {
    const float* x       = (const float*)d_in[0];
    const float* center  = (const float*)d_in[1];
    const float* scaling = (const float*)d_in[2];
    float* out = (float*)d_out;

    int B = in_sizes[0];
    int N = in_sizes[1];
    int T = (int)((long long)out_size / ((long long)B * (long long)N));

    bool bpow2 = (B & (B - 1)) == 0;
    long long rows = (long long)T * B;
    if (N == 16 && bpow2 && (B % 4096) == 0 && (rows % 4096) == 0) {
        int logB = 0;
        while ((1 << logB) < B) ++logB;
        int nblocks = (int)(rows >> 12);   // 4096 rows (256 KiB) per block
        rf_encode_lin<<<nblocks, 256, 0, stream>>>(x, center, scaling, out,
                                                   logB, B - 1, T);
    } else {
        const int block = 256;
        int blocks = (int)((rows + block - 1) / block);
        rf_encode_generic<<<blocks, block, 0, stream>>>(x, center, scaling, out, B, N, T);
    }
}